// Round 22
// baseline (237.012 us; speedup 1.0000x reference)
//
#include <hip/hip_runtime.h>

// ---------------------------------------------------------------------------
// MultilevelSelfAttentionBlockWithRoPE on MI355X (gfx950)
// fused_pre(LN + W transposes) -> QKV GEMM (BK=64) -> fused rope+vtrans ->
// flash attn (64-key tiles, 4 waves x 16 q, pair-major) -> out GEMM
// (64x128, BK=64) + residual.
// R22 = R19/R21 (verified best 169.7-170.0) + ONE knob:
//   attn __launch_bounds__(256,4) -> (256,8).
// Rationale: attn VGPR_Count=48 <= 64 (8-waves/SIMD quantization), LDS
// 8x18432=147KB <= 160KB, wave slots 8x4=32=max -> the whole 2048-block
// grid can be co-resident at 8 blocks/CU.  (256,4) was self-capping
// occupancy at 32%.  R14 proved attn scales with waves/CU (12->16 waves:
// 94->67us); 16->32 waves should close the remaining latency gaps.
// ---------------------------------------------------------------------------

typedef float  f32x4  __attribute__((ext_vector_type(4)));
typedef __bf16 bf16x8 __attribute__((ext_vector_type(8)));
typedef __bf16 bf16x4 __attribute__((ext_vector_type(4)));
typedef short  s16x4  __attribute__((ext_vector_type(4)));
typedef short  s16x8  __attribute__((ext_vector_type(8)));
typedef unsigned short u16x4 __attribute__((ext_vector_type(4)));

typedef __attribute__((address_space(1))) void as1_void_t;
typedef __attribute__((address_space(3))) void as3_void_t;

static __device__ __forceinline__ unsigned short f2bf(float f) {
  unsigned int u = __float_as_uint(f);
  u += 0x7fffu + ((u >> 16) & 1u);          // round-to-nearest-even
  return (unsigned short)(u >> 16);
}
static __device__ __forceinline__ float bf2f(unsigned short s) {
  return __uint_as_float(((unsigned int)s) << 16);
}

static __device__ __forceinline__ void gload_lds16(const void* g, void* l) {
  __builtin_amdgcn_global_load_lds((as1_void_t*)g, (as3_void_t*)l, 16, 0, 0);
}

static __device__ __forceinline__ f32x4 mfma32(bf16x8 a, bf16x8 b, f32x4 c) {
  return __builtin_amdgcn_mfma_f32_16x16x32_bf16(a, b, c, 0, 0, 0);
}
static __device__ __forceinline__ f32x4 mfma16(s16x4 a, s16x4 b, f32x4 c) {
  return __builtin_amdgcn_mfma_f32_16x16x16bf16_1k(a, b, c, 0, 0, 0);
}

// ---------------------------------------------------------------------------
// fused_pre: LN (blocks [0, N/4)) + wqkv transpose (next 768) + wout
// transpose (next 256).  Block-uniform dispatch; all paths 256 threads.
// ---------------------------------------------------------------------------
__global__ __launch_bounds__(256) void fused_pre(
    const float* __restrict__ x, const float* __restrict__ gamma,
    const float* __restrict__ beta, unsigned short* __restrict__ h,
    const float* __restrict__ wqkv, unsigned short* __restrict__ wqkvT,
    const float* __restrict__ wout, unsigned short* __restrict__ woutT,
    int Ntok) {
  __shared__ unsigned short tile[64][65];
  int blk = blockIdx.x, t = threadIdx.x;
  int lnB = Ntok >> 2;
  if (blk < lnB) {
    // ---- LayerNorm: one wave per row ----
    int row  = blk * 4 + (t >> 6);
    int lane = t & 63;
    const float* xr = x + (size_t)row * 1024;
    f32x4 v[4];
    float s = 0.f, ss = 0.f;
#pragma unroll
    for (int c = 0; c < 4; ++c) {
      v[c] = *(const f32x4*)(xr + c * 256 + lane * 4);
#pragma unroll
      for (int j = 0; j < 4; ++j) { s += v[c][j]; ss += v[c][j] * v[c][j]; }
    }
#pragma unroll
    for (int d = 1; d < 64; d <<= 1) {
      s  += __shfl_xor(s, d);
      ss += __shfl_xor(ss, d);
    }
    float mu  = s * (1.f / 1024.f);
    float var = ss * (1.f / 1024.f) - mu * mu;
    float inv = rsqrtf(var + 1e-5f);
#pragma unroll
    for (int c = 0; c < 4; ++c) {
      f32x4 gv = *(const f32x4*)(gamma + c * 256 + lane * 4);
      f32x4 bv = *(const f32x4*)(beta  + c * 256 + lane * 4);
      u16x4 hv;
#pragma unroll
      for (int j = 0; j < 4; ++j)
        hv[j] = f2bf((v[c][j] - mu) * inv * gv[j] + bv[j]);
      *(u16x4*)(h + (size_t)row * 1024 + c * 256 + lane * 4) = hv;
    }
  } else {
    // ---- transpose+convert f32 [R][C] -> bf16 [C][R] ----
    const float* in;
    unsigned short* out;
    int R = 1024, C, c0, r0;
    if (blk < lnB + 768) {
      int idx = blk - lnB;
      in = wqkv; out = wqkvT; C = 3072;
      c0 = (idx % 48) * 64; r0 = (idx / 48) * 64;
    } else {
      int idx = blk - lnB - 768;
      in = wout; out = woutT; C = 1024;
      c0 = (idx & 15) * 64; r0 = (idx >> 4) * 64;
    }
    int tr = t >> 6, tc = t & 63;
#pragma unroll
    for (int i = 0; i < 16; ++i) {
      int rr = i * 4 + tr;
      tile[tc][rr] = f2bf(in[(size_t)(r0 + rr) * C + c0 + tc]);
    }
    __syncthreads();
#pragma unroll
    for (int i = 0; i < 16; ++i) {
      int cc = i * 4 + tr;
      out[(size_t)(c0 + cc) * R + r0 + tc] = tile[cc][tc];
    }
  }
}

// ---------------------------------------------------------------------------
// GEMM (QKV): C = A * Bt^T, scatter bf16 into QKV planes [3][16][M][64].
// BK=64 as two BK-32 subtiles (R16-verified).
// ---------------------------------------------------------------------------
__global__ __launch_bounds__(256) void gemm_qkv(
    const unsigned short* __restrict__ A, const unsigned short* __restrict__ Bt,
    unsigned short* __restrict__ Cqkv, int M, int K) {
  __shared__ unsigned short Alds[2][128 * 32];
  __shared__ unsigned short Blds[2][128 * 32];
  int n0 = blockIdx.x * 128, m0 = blockIdx.y * 128;
  int t = threadIdx.x, lane = t & 63, wave = t >> 6;
  int wr = wave >> 1, wc = wave & 1;
  int r = lane & 15, g = lane >> 4;
  f32x4 acc[4][4] = {};

  int srow = lane >> 2;
  int scol = (lane & 3) * 8;

  for (int k0 = 0; k0 < K; k0 += 64) {
    __syncthreads();
#pragma unroll
    for (int half = 0; half < 2; ++half)
#pragma unroll
      for (int c = 0; c < 2; ++c) {
        int seg = wave * 2 + c;
        gload_lds16(A  + (size_t)(m0 + seg * 16 + srow) * K + k0 + half * 32 + scol,
                    Alds[half] + seg * 16 * 32);
        gload_lds16(Bt + (size_t)(n0 + seg * 16 + srow) * K + k0 + half * 32 + scol,
                    Blds[half] + seg * 16 * 32);
      }
    __syncthreads();
#pragma unroll
    for (int half = 0; half < 2; ++half) {
      bf16x8 a[4], b[4];
#pragma unroll
      for (int m = 0; m < 4; ++m)
        a[m] = *(const bf16x8*)(Alds[half] + (wr * 64 + m * 16 + r) * 32 + g * 8);
#pragma unroll
      for (int n = 0; n < 4; ++n)
        b[n] = *(const bf16x8*)(Blds[half] + (wc * 64 + n * 16 + r) * 32 + g * 8);
#pragma unroll
      for (int m = 0; m < 4; ++m)
#pragma unroll
        for (int n = 0; n < 4; ++n)
          acc[m][n] = mfma32(a[m], b[n], acc[m][n]);
    }
  }

#pragma unroll
  for (int mi = 0; mi < 4; ++mi) {
    int grow0 = m0 + wr * 64 + mi * 16 + g * 4;
#pragma unroll
    for (int ni = 0; ni < 4; ++ni) {
      int gcol = n0 + wc * 64 + ni * 16 + r;
      f32x4 v = acc[mi][ni];
#pragma unroll
      for (int e = 0; e < 4; ++e) {
        int which = gcol >> 10, rem = gcol & 1023, hh = rem >> 6, d = rem & 63;
        Cqkv[((size_t)(which * 16 + hh) * M + grow0 + e) * 64 + d] = f2bf(v[e]);
      }
    }
  }
}

// ---------------------------------------------------------------------------
// out-GEMM: Cf = A * Bt^T + residual.  64x128 tile, BK=64 (two subtiles),
// 768 blocks = 3/CU.
// ---------------------------------------------------------------------------
__global__ __launch_bounds__(256) void gemm_out64(
    const unsigned short* __restrict__ A, const unsigned short* __restrict__ Bt,
    const float* __restrict__ residual, float* __restrict__ Cf,
    int M, int Ncols, int K) {
  __shared__ unsigned short Alds[2][64 * 32];
  __shared__ unsigned short Blds[2][128 * 32];
  int n0 = blockIdx.x * 128, m0 = blockIdx.y * 64;
  int t = threadIdx.x, lane = t & 63, wave = t >> 6;
  int wr = wave >> 1, wc = wave & 1;
  int r = lane & 15, g = lane >> 4;
  f32x4 acc[2][4] = {};

  int srow = lane >> 2;
  int scol = (lane & 3) * 8;

  for (int k0 = 0; k0 < K; k0 += 64) {
    __syncthreads();
#pragma unroll
    for (int half = 0; half < 2; ++half) {
      gload_lds16(A + (size_t)(m0 + wave * 16 + srow) * K + k0 + half * 32 + scol,
                  Alds[half] + wave * 16 * 32);
#pragma unroll
      for (int c = 0; c < 2; ++c) {
        int seg = wave * 2 + c;
        gload_lds16(Bt + (size_t)(n0 + seg * 16 + srow) * K + k0 + half * 32 + scol,
                    Blds[half] + seg * 16 * 32);
      }
    }
    __syncthreads();
#pragma unroll
    for (int half = 0; half < 2; ++half) {
      bf16x8 a[2], b[4];
#pragma unroll
      for (int m = 0; m < 2; ++m)
        a[m] = *(const bf16x8*)(Alds[half] + (wr * 32 + m * 16 + r) * 32 + g * 8);
#pragma unroll
      for (int n = 0; n < 4; ++n)
        b[n] = *(const bf16x8*)(Blds[half] + (wc * 64 + n * 16 + r) * 32 + g * 8);
#pragma unroll
      for (int m = 0; m < 2; ++m)
#pragma unroll
        for (int n = 0; n < 4; ++n)
          acc[m][n] = mfma32(a[m], b[n], acc[m][n]);
    }
  }

#pragma unroll
  for (int mi = 0; mi < 2; ++mi) {
    int grow0 = m0 + wr * 32 + mi * 16 + g * 4;
#pragma unroll
    for (int ni = 0; ni < 4; ++ni) {
      int gcol = n0 + wc * 64 + ni * 16 + r;
      f32x4 v = acc[mi][ni];
#pragma unroll
      for (int e = 0; e < 4; ++e)
        Cf[(size_t)(grow0 + e) * Ncols + gcol] =
            v[e] + residual[(size_t)(grow0 + e) * Ncols + gcol];
    }
  }
}

// ---------------------------------------------------------------------------
// rope_vtrans: RoPE on Q,K planes (blocks [0, N*2)) + V transpose into VtG
// (blocks [N*2, N*2 + 16*N/64)).  Block-uniform dispatch, 256 threads.
// ---------------------------------------------------------------------------
__global__ __launch_bounds__(256) void rope_vtrans(
    unsigned short* __restrict__ QKV, unsigned short* __restrict__ VtG,
    const float* __restrict__ pos, const float* __restrict__ freqs, int Ntok) {
  __shared__ unsigned short tile[64][72];
  int blk = blockIdx.x, tid = threadIdx.x;
  int ropeB = Ntok * 2;                   // (Ntok*512)/256
  if (blk < ropeB) {
    int t = blk * 256 + tid;
    int kk = t & 31, h = (t >> 5) & 15, i = t >> 9;
    float lvlf = pos[i * 3 + 0];
    float py   = pos[i * 3 + 1];
    float px   = pos[i * 3 + 2];
    int lvl = (int)lvlf;
    lvl = lvl < 0 ? 0 : (lvl > 3 ? 3 : lvl);
    const float* fp = freqs + (((lvl * 16 + h) * 32 + kk) << 1);
    float ang = fp[0] * py + fp[1] * px;
    float s, c;
    __sincosf(ang, &s, &c);
    size_t qoff = ((size_t)h * Ntok + i) * 64 + 2 * kk;
    size_t koff = qoff + (size_t)16 * Ntok * 64;
    unsigned int q2 = *(const unsigned int*)(QKV + qoff);
    float qa = bf2f((unsigned short)(q2 & 0xffff));
    float qb = bf2f((unsigned short)(q2 >> 16));
    *(unsigned int*)(QKV + qoff) =
        (unsigned int)f2bf(qa * c - qb * s) |
        ((unsigned int)f2bf(qa * s + qb * c) << 16);
    unsigned int k2 = *(const unsigned int*)(QKV + koff);
    float ka = bf2f((unsigned short)(k2 & 0xffff));
    float kb = bf2f((unsigned short)(k2 >> 16));
    *(unsigned int*)(QKV + koff) =
        (unsigned int)f2bf(ka * c - kb * s) |
        ((unsigned int)f2bf(ka * s + kb * c) << 16);
  } else {
    const unsigned short* Vp = QKV + (size_t)32 * Ntok * 64;
    int b2 = blk - ropeB;
    int h = b2 & 15, t0 = (b2 >> 4) * 64;
    {
      int tok = tid >> 2, dc = (tid & 3) * 16;
      const unsigned short* src = Vp + ((size_t)h * Ntok + t0 + tok) * 64 + dc;
      *(s16x8*)&tile[tok][dc]     = *(const s16x8*)src;
      *(s16x8*)&tile[tok][dc + 8] = *(const s16x8*)(src + 8);
    }
    __syncthreads();
    {
      int d = tid >> 2, tc = (tid & 3) * 16;
      s16x8 o0, o1;
#pragma unroll
      for (int j = 0; j < 8; ++j) {
        o0[j] = (short)tile[tc + j][d];
        o1[j] = (short)tile[tc + 8 + j][d];
      }
      unsigned short* dst = VtG + (size_t)(h * 64 + d) * Ntok + t0 + tc;
      *(s16x8*)dst       = o0;
      *(s16x8*)(dst + 8) = o1;
    }
  }
}

// ---------------------------------------------------------------------------
// Flash attention (R14/R17/R19-verified structure).  Block = (batch, head,
// 64 q rows); 4 waves x 16 q rows.  Pair-major enumeration.  S^T = K*Q^T;
// online softmax (log2, lazy defer-max, row-sums via ones-MFMA); K/VtG
// staged in LDS; raw-barrier pipeline with reg prefetch; pair->XCD mapping.
// R22: launch_bounds (256,8) -> 8 blocks/CU (VGPR 48<=64, LDS 147<=160KB,
// 32 wave slots) = whole grid co-resident.
// ---------------------------------------------------------------------------
__global__ __launch_bounds__(256, 8) void attn_kernel(
    const unsigned short* __restrict__ QKV,
    const unsigned short* __restrict__ VtG, const int* __restrict__ boff,
    unsigned short* __restrict__ O, int Ntok) {
  __shared__ unsigned short Klds[64][72];
  __shared__ unsigned short Vt[64][72];   // Vt[d][key]
  const float SCALE_LOG2 = 0.125f * 1.44269504088896340736f;
  const s16x4 ones16 = {(short)0x3F80, (short)0x3F80, (short)0x3F80, (short)0x3F80};

  // pair-major mapping: grid = 2048 = 8 xcd * 16 pairs * 16 qblk
  int bid = blockIdx.x;
  int x = bid & 7, i = bid >> 3;
  int qblk = i & 15;
  int p = x + 8 * (i >> 4);               // (b,h) pair, resident on XCD x
  int h = p & 15, b = p >> 4;
  int off = boff[b], len = boff[b + 1] - off;
  int q0 = qblk * 64;
  if (q0 >= len) return;
  int t = threadIdx.x, lane = t & 63, wave = t >> 6;
  int r = lane & 15, g4 = lane >> 4;
  const unsigned short* Qg = QKV + (size_t)h * Ntok * 64;
  const unsigned short* Kg = QKV + (size_t)(16 + h) * Ntok * 64;
  int qmax = off + len - 1;

  bf16x8 qf[2];
  {
    int qtok = off + q0 + wave * 16 + r;
    if (qtok > qmax) qtok = qmax;
#pragma unroll
    for (int c = 0; c < 2; ++c)
      qf[c] = *(const bf16x8*)(Qg + (size_t)qtok * 64 + c * 32 + g4 * 8);
  }

  float m = -1e30f;
  f32x4 o[4] = {};
  f32x4 o_sum = {};                       // row-sums of P via ones-MFMA

  // staging (256 threads): thread t stages K row t>>2 shorts [(t&3)*16,+16)
  // and Vt row t>>2 keys [(t&3)*16,+16).
  int srow = t >> 2, sseg = t & 3;
  const unsigned short* Vrow = VtG + (size_t)(h * 64 + srow) * Ntok;

  s16x8 kr[2], vr[2];
  {
    int ktok = off + srow; if (ktok > qmax) ktok = qmax;
#pragma unroll
    for (int c = 0; c < 2; ++c)
      kr[c] = *(const s16x8*)(Kg + (size_t)ktok * 64 + sseg * 16 + c * 8);
#pragma unroll
    for (int c = 0; c < 2; ++c) {
      int tc = sseg * 16 + c * 8; if (tc + 8 > len) tc = len - 8;
      vr[c] = *(const s16x8*)(Vrow + off + tc);
    }
  }

  for (int kt = 0; kt < len; kt += 64) {
    // (A) previous tile's LDS reads complete
    asm volatile("s_waitcnt lgkmcnt(0)" ::: "memory");
    __builtin_amdgcn_s_barrier();
    __builtin_amdgcn_sched_barrier(0);
#pragma unroll
    for (int c = 0; c < 2; ++c) {
      *(s16x8*)&Klds[srow][sseg * 16 + c * 8] = kr[c];
      *(s16x8*)&Vt[srow][sseg * 16 + c * 8]   = vr[c];
    }
    int ktn = kt + 64;
    if (ktn < len) {   // issue prefetch; stays in flight through compute
      int ktok = off + ktn + srow; if (ktok > qmax) ktok = qmax;
#pragma unroll
      for (int c = 0; c < 2; ++c)
        kr[c] = *(const s16x8*)(Kg + (size_t)ktok * 64 + sseg * 16 + c * 8);
#pragma unroll
      for (int c = 0; c < 2; ++c) {
        int tc = ktn + sseg * 16 + c * 8; if (tc + 8 > len) tc = len - 8;
        vr[c] = *(const s16x8*)(Vrow + off + tc);
      }
    }
    // (B) own ds_writes visible; do NOT drain vmcnt (prefetch stays async)
    asm volatile("s_waitcnt lgkmcnt(0)" ::: "memory");
    __builtin_amdgcn_s_barrier();
    __builtin_amdgcn_sched_barrier(0);

    // ---- scores: S^T[key][q], 64 keys x 16 q rows -----------------------
    f32x4 s[4];
    __builtin_amdgcn_s_setprio(1);
#pragma unroll
    for (int sub = 0; sub < 4; ++sub) {
      bf16x8 ka0 = *(const bf16x8*)(&Klds[sub * 16 + r][g4 * 8]);
      bf16x8 ka1 = *(const bf16x8*)(&Klds[sub * 16 + r][32 + g4 * 8]);
      f32x4 acc = {};
      acc = mfma32(ka0, qf[0], acc);
      acc = mfma32(ka1, qf[1], acc);
      s[sub] = acc;
    }
    __builtin_amdgcn_s_setprio(0);

    bool tail = (kt + 64 > len);
    s16x4 pf[4];
    {
      float sc[4][4];                      // raw scores (masked)
      float ms[4];
#pragma unroll
      for (int sub = 0; sub < 4; ++sub) {
#pragma unroll
        for (int e = 0; e < 4; ++e) {
          float v = s[sub][e];
          if (tail && (kt + sub * 16 + 4 * g4 + e >= len)) v = -1e30f;
          sc[sub][e] = v;
        }
        ms[sub] = fmaxf(fmaxf(sc[sub][0], sc[sub][1]),
                        fmaxf(sc[sub][2], sc[sub][3]));
      }
      float tmax = fmaxf(fmaxf(ms[0], ms[1]), fmaxf(ms[2], ms[3]));
      // lazy defer-max: per-lane check, no shuffles in the common case
      if (!__all(tmax * SCALE_LOG2 <= m + 8.f)) {
        float tm = tmax * SCALE_LOG2;
        tm = fmaxf(tm, __shfl_xor(tm, 16));
        tm = fmaxf(tm, __shfl_xor(tm, 32));
        float mnew = fmaxf(m, tm);
        float alpha = exp2f(m - mnew);     // wave-uniform
        m = mnew;
#pragma unroll
        for (int e = 0; e < 4; ++e) o_sum[e] *= alpha;
#pragma unroll
        for (int dt = 0; dt < 4; ++dt)
#pragma unroll
          for (int e = 0; e < 4; ++e) o[dt][e] *= alpha;
      }
#pragma unroll
      for (int sub = 0; sub < 4; ++sub) {
        bf16x4 pb;
#pragma unroll
        for (int e = 0; e < 4; ++e)
          pb[e] = (__bf16)exp2f(fmaf(sc[sub][e], SCALE_LOG2, -m));
        pf[sub] = __builtin_bit_cast(s16x4, pb);
      }
    }

    // ---- PV: O += P * V ; row-sums via ones-MFMA ------------------------
    __builtin_amdgcn_s_setprio(1);
#pragma unroll
    for (int sub = 0; sub < 4; ++sub)
      o_sum = mfma16(pf[sub], ones16, o_sum);
#pragma unroll
    for (int dt = 0; dt < 4; ++dt)
#pragma unroll
      for (int sub = 0; sub < 4; ++sub) {
        s16x4 vf = *(const s16x4*)(&Vt[dt * 16 + r][sub * 16 + 4 * g4]);
        o[dt] = mfma16(pf[sub], vf, o[dt]);
      }
    __builtin_amdgcn_s_setprio(0);
  }

  {
    float il[4];
#pragma unroll
    for (int e = 0; e < 4; ++e) il[e] = 1.0f / o_sum[e];
#pragma unroll
    for (int dt = 0; dt < 4; ++dt)
#pragma unroll
      for (int e = 0; e < 4; ++e) {
        int tl = q0 + wave * 16 + 4 * g4 + e;
        if (tl < len)
          O[(size_t)(off + tl) * 1024 + h * 64 + dt * 16 + r] =
              f2bf(o[dt][e] * il[e]);
      }
  }
}

// ---------------------------------------------------------------------------
extern "C" void kernel_launch(void* const* d_in, const int* in_sizes, int n_in,
                              void* d_out, int out_size, void* d_ws, size_t ws_size,
                              hipStream_t stream) {
  const float* x     = (const float*)d_in[0];
  const float* pos   = (const float*)d_in[1];
  const int*   boff  = (const int*)d_in[2];
  const float* gamma = (const float*)d_in[3];
  const float* beta  = (const float*)d_in[4];
  const float* wqkv  = (const float*)d_in[5];
  const float* wout  = (const float*)d_in[6];
  const float* freqs = (const float*)d_in[7];
  float* out = (float*)d_out;
  int N  = in_sizes[0] / 1024;   // 6144
  int Bn = in_sizes[2] - 1;      // 8

  char* ws = (char*)d_ws;
  unsigned short* wqkvT = (unsigned short*)ws;                          // 6 MiB
  unsigned short* woutT = (unsigned short*)(ws + (size_t)3072 * 1024 * 2);
  unsigned short* QKV   = (unsigned short*)(ws + (size_t)3072 * 1024 * 2 +
                                            (size_t)1024 * 1024 * 2);
  size_t qkvBytes = (size_t)48 * N * 64 * 2;                            // 36 MiB
  unsigned short* hbuf = (unsigned short*)((char*)QKV + qkvBytes);      // 12 MiB
  unsigned short* VtG  = hbuf;                       // hbuf dead after gemm_qkv
  unsigned short* Vp   = QKV + (size_t)32 * N * 64;  // V plane (row-major)
  unsigned short* Obuf = Vp;                         // V plane dead after vtrans

  fused_pre<<<N / 4 + 768 + 256, 256, 0, stream>>>(
      x, gamma, beta, hbuf, wqkv, wqkvT, wout, woutT, N);
  gemm_qkv<<<dim3(3072 / 128, N / 128), 256, 0, stream>>>(
      hbuf, wqkvT, QKV, N, 1024);
  rope_vtrans<<<N * 2 + 16 * (N / 64), 256, 0, stream>>>(
      QKV, VtG, pos, freqs, N);
  attn_kernel<<<8 * 16 * 16, 256, 0, stream>>>(QKV, VtG, boff, Obuf, N);
  gemm_out64<<<dim3(1024 / 128, N / 64), 256, 0, stream>>>(
      Obuf, woutT, x, out, N, 1024, 1024);
}

// Round 23
// 169.661 us; speedup vs baseline: 1.3970x; 1.3970x over previous
//
#include <hip/hip_runtime.h>

// ---------------------------------------------------------------------------
// MultilevelSelfAttentionBlockWithRoPE on MI355X (gfx950)
// fused_pre(LN + W transposes) -> QKV GEMM (BK=64) -> fused rope+vtrans ->
// flash attn (64-key tiles, 4 waves x 16 q, pair-major) -> out GEMM
// (64x128, BK=64) + residual.
// R23 = exact revert to R19/R21 (verified best 169.7-170.0us, 3x).
// R22 post-mortem: (256,8) forced a 32-VGPR budget (was 48) -> 304MB of
// scratch spill traffic, attn 66->149us.  Third spill failure (R4, R20,
// R22): this attn kernel is register-bound at the 4-blocks/CU point;
// occupancy-via-launch-bounds is refuted.  (256,4) is the optimum.
// ---------------------------------------------------------------------------

typedef float  f32x4  __attribute__((ext_vector_type(4)));
typedef __bf16 bf16x8 __attribute__((ext_vector_type(8)));
typedef __bf16 bf16x4 __attribute__((ext_vector_type(4)));
typedef short  s16x4  __attribute__((ext_vector_type(4)));
typedef short  s16x8  __attribute__((ext_vector_type(8)));
typedef unsigned short u16x4 __attribute__((ext_vector_type(4)));

typedef __attribute__((address_space(1))) void as1_void_t;
typedef __attribute__((address_space(3))) void as3_void_t;

static __device__ __forceinline__ unsigned short f2bf(float f) {
  unsigned int u = __float_as_uint(f);
  u += 0x7fffu + ((u >> 16) & 1u);          // round-to-nearest-even
  return (unsigned short)(u >> 16);
}
static __device__ __forceinline__ float bf2f(unsigned short s) {
  return __uint_as_float(((unsigned int)s) << 16);
}

static __device__ __forceinline__ void gload_lds16(const void* g, void* l) {
  __builtin_amdgcn_global_load_lds((as1_void_t*)g, (as3_void_t*)l, 16, 0, 0);
}

static __device__ __forceinline__ f32x4 mfma32(bf16x8 a, bf16x8 b, f32x4 c) {
  return __builtin_amdgcn_mfma_f32_16x16x32_bf16(a, b, c, 0, 0, 0);
}
static __device__ __forceinline__ f32x4 mfma16(s16x4 a, s16x4 b, f32x4 c) {
  return __builtin_amdgcn_mfma_f32_16x16x16bf16_1k(a, b, c, 0, 0, 0);
}

// ---------------------------------------------------------------------------
// fused_pre: LN (blocks [0, N/4)) + wqkv transpose (next 768) + wout
// transpose (next 256).  Block-uniform dispatch; all paths 256 threads.
// ---------------------------------------------------------------------------
__global__ __launch_bounds__(256) void fused_pre(
    const float* __restrict__ x, const float* __restrict__ gamma,
    const float* __restrict__ beta, unsigned short* __restrict__ h,
    const float* __restrict__ wqkv, unsigned short* __restrict__ wqkvT,
    const float* __restrict__ wout, unsigned short* __restrict__ woutT,
    int Ntok) {
  __shared__ unsigned short tile[64][65];
  int blk = blockIdx.x, t = threadIdx.x;
  int lnB = Ntok >> 2;
  if (blk < lnB) {
    // ---- LayerNorm: one wave per row ----
    int row  = blk * 4 + (t >> 6);
    int lane = t & 63;
    const float* xr = x + (size_t)row * 1024;
    f32x4 v[4];
    float s = 0.f, ss = 0.f;
#pragma unroll
    for (int c = 0; c < 4; ++c) {
      v[c] = *(const f32x4*)(xr + c * 256 + lane * 4);
#pragma unroll
      for (int j = 0; j < 4; ++j) { s += v[c][j]; ss += v[c][j] * v[c][j]; }
    }
#pragma unroll
    for (int d = 1; d < 64; d <<= 1) {
      s  += __shfl_xor(s, d);
      ss += __shfl_xor(ss, d);
    }
    float mu  = s * (1.f / 1024.f);
    float var = ss * (1.f / 1024.f) - mu * mu;
    float inv = rsqrtf(var + 1e-5f);
#pragma unroll
    for (int c = 0; c < 4; ++c) {
      f32x4 gv = *(const f32x4*)(gamma + c * 256 + lane * 4);
      f32x4 bv = *(const f32x4*)(beta  + c * 256 + lane * 4);
      u16x4 hv;
#pragma unroll
      for (int j = 0; j < 4; ++j)
        hv[j] = f2bf((v[c][j] - mu) * inv * gv[j] + bv[j]);
      *(u16x4*)(h + (size_t)row * 1024 + c * 256 + lane * 4) = hv;
    }
  } else {
    // ---- transpose+convert f32 [R][C] -> bf16 [C][R] ----
    const float* in;
    unsigned short* out;
    int R = 1024, C, c0, r0;
    if (blk < lnB + 768) {
      int idx = blk - lnB;
      in = wqkv; out = wqkvT; C = 3072;
      c0 = (idx % 48) * 64; r0 = (idx / 48) * 64;
    } else {
      int idx = blk - lnB - 768;
      in = wout; out = woutT; C = 1024;
      c0 = (idx & 15) * 64; r0 = (idx >> 4) * 64;
    }
    int tr = t >> 6, tc = t & 63;
#pragma unroll
    for (int i = 0; i < 16; ++i) {
      int rr = i * 4 + tr;
      tile[tc][rr] = f2bf(in[(size_t)(r0 + rr) * C + c0 + tc]);
    }
    __syncthreads();
#pragma unroll
    for (int i = 0; i < 16; ++i) {
      int cc = i * 4 + tr;
      out[(size_t)(c0 + cc) * R + r0 + tc] = tile[cc][tc];
    }
  }
}

// ---------------------------------------------------------------------------
// GEMM (QKV): C = A * Bt^T, scatter bf16 into QKV planes [3][16][M][64].
// BK=64 as two BK-32 subtiles (R16-verified).
// ---------------------------------------------------------------------------
__global__ __launch_bounds__(256) void gemm_qkv(
    const unsigned short* __restrict__ A, const unsigned short* __restrict__ Bt,
    unsigned short* __restrict__ Cqkv, int M, int K) {
  __shared__ unsigned short Alds[2][128 * 32];
  __shared__ unsigned short Blds[2][128 * 32];
  int n0 = blockIdx.x * 128, m0 = blockIdx.y * 128;
  int t = threadIdx.x, lane = t & 63, wave = t >> 6;
  int wr = wave >> 1, wc = wave & 1;
  int r = lane & 15, g = lane >> 4;
  f32x4 acc[4][4] = {};

  int srow = lane >> 2;
  int scol = (lane & 3) * 8;

  for (int k0 = 0; k0 < K; k0 += 64) {
    __syncthreads();
#pragma unroll
    for (int half = 0; half < 2; ++half)
#pragma unroll
      for (int c = 0; c < 2; ++c) {
        int seg = wave * 2 + c;
        gload_lds16(A  + (size_t)(m0 + seg * 16 + srow) * K + k0 + half * 32 + scol,
                    Alds[half] + seg * 16 * 32);
        gload_lds16(Bt + (size_t)(n0 + seg * 16 + srow) * K + k0 + half * 32 + scol,
                    Blds[half] + seg * 16 * 32);
      }
    __syncthreads();
#pragma unroll
    for (int half = 0; half < 2; ++half) {
      bf16x8 a[4], b[4];
#pragma unroll
      for (int m = 0; m < 4; ++m)
        a[m] = *(const bf16x8*)(Alds[half] + (wr * 64 + m * 16 + r) * 32 + g * 8);
#pragma unroll
      for (int n = 0; n < 4; ++n)
        b[n] = *(const bf16x8*)(Blds[half] + (wc * 64 + n * 16 + r) * 32 + g * 8);
#pragma unroll
      for (int m = 0; m < 4; ++m)
#pragma unroll
        for (int n = 0; n < 4; ++n)
          acc[m][n] = mfma32(a[m], b[n], acc[m][n]);
    }
  }

#pragma unroll
  for (int mi = 0; mi < 4; ++mi) {
    int grow0 = m0 + wr * 64 + mi * 16 + g * 4;
#pragma unroll
    for (int ni = 0; ni < 4; ++ni) {
      int gcol = n0 + wc * 64 + ni * 16 + r;
      f32x4 v = acc[mi][ni];
#pragma unroll
      for (int e = 0; e < 4; ++e) {
        int which = gcol >> 10, rem = gcol & 1023, hh = rem >> 6, d = rem & 63;
        Cqkv[((size_t)(which * 16 + hh) * M + grow0 + e) * 64 + d] = f2bf(v[e]);
      }
    }
  }
}

// ---------------------------------------------------------------------------
// out-GEMM: Cf = A * Bt^T + residual.  64x128 tile, BK=64 (two subtiles),
// 768 blocks = 3/CU.
// ---------------------------------------------------------------------------
__global__ __launch_bounds__(256) void gemm_out64(
    const unsigned short* __restrict__ A, const unsigned short* __restrict__ Bt,
    const float* __restrict__ residual, float* __restrict__ Cf,
    int M, int Ncols, int K) {
  __shared__ unsigned short Alds[2][64 * 32];
  __shared__ unsigned short Blds[2][128 * 32];
  int n0 = blockIdx.x * 128, m0 = blockIdx.y * 64;
  int t = threadIdx.x, lane = t & 63, wave = t >> 6;
  int wr = wave >> 1, wc = wave & 1;
  int r = lane & 15, g = lane >> 4;
  f32x4 acc[2][4] = {};

  int srow = lane >> 2;
  int scol = (lane & 3) * 8;

  for (int k0 = 0; k0 < K; k0 += 64) {
    __syncthreads();
#pragma unroll
    for (int half = 0; half < 2; ++half) {
      gload_lds16(A + (size_t)(m0 + wave * 16 + srow) * K + k0 + half * 32 + scol,
                  Alds[half] + wave * 16 * 32);
#pragma unroll
      for (int c = 0; c < 2; ++c) {
        int seg = wave * 2 + c;
        gload_lds16(Bt + (size_t)(n0 + seg * 16 + srow) * K + k0 + half * 32 + scol,
                    Blds[half] + seg * 16 * 32);
      }
    }
    __syncthreads();
#pragma unroll
    for (int half = 0; half < 2; ++half) {
      bf16x8 a[2], b[4];
#pragma unroll
      for (int m = 0; m < 2; ++m)
        a[m] = *(const bf16x8*)(Alds[half] + (wr * 32 + m * 16 + r) * 32 + g * 8);
#pragma unroll
      for (int n = 0; n < 4; ++n)
        b[n] = *(const bf16x8*)(Blds[half] + (wc * 64 + n * 16 + r) * 32 + g * 8);
#pragma unroll
      for (int m = 0; m < 2; ++m)
#pragma unroll
        for (int n = 0; n < 4; ++n)
          acc[m][n] = mfma32(a[m], b[n], acc[m][n]);
    }
  }

#pragma unroll
  for (int mi = 0; mi < 2; ++mi) {
    int grow0 = m0 + wr * 32 + mi * 16 + g * 4;
#pragma unroll
    for (int ni = 0; ni < 4; ++ni) {
      int gcol = n0 + wc * 64 + ni * 16 + r;
      f32x4 v = acc[mi][ni];
#pragma unroll
      for (int e = 0; e < 4; ++e)
        Cf[(size_t)(grow0 + e) * Ncols + gcol] =
            v[e] + residual[(size_t)(grow0 + e) * Ncols + gcol];
    }
  }
}

// ---------------------------------------------------------------------------
// rope_vtrans: RoPE on Q,K planes (blocks [0, N*2)) + V transpose into VtG
// (blocks [N*2, N*2 + 16*N/64)).  Block-uniform dispatch, 256 threads.
// ---------------------------------------------------------------------------
__global__ __launch_bounds__(256) void rope_vtrans(
    unsigned short* __restrict__ QKV, unsigned short* __restrict__ VtG,
    const float* __restrict__ pos, const float* __restrict__ freqs, int Ntok) {
  __shared__ unsigned short tile[64][72];
  int blk = blockIdx.x, tid = threadIdx.x;
  int ropeB = Ntok * 2;                   // (Ntok*512)/256
  if (blk < ropeB) {
    int t = blk * 256 + tid;
    int kk = t & 31, h = (t >> 5) & 15, i = t >> 9;
    float lvlf = pos[i * 3 + 0];
    float py   = pos[i * 3 + 1];
    float px   = pos[i * 3 + 2];
    int lvl = (int)lvlf;
    lvl = lvl < 0 ? 0 : (lvl > 3 ? 3 : lvl);
    const float* fp = freqs + (((lvl * 16 + h) * 32 + kk) << 1);
    float ang = fp[0] * py + fp[1] * px;
    float s, c;
    __sincosf(ang, &s, &c);
    size_t qoff = ((size_t)h * Ntok + i) * 64 + 2 * kk;
    size_t koff = qoff + (size_t)16 * Ntok * 64;
    unsigned int q2 = *(const unsigned int*)(QKV + qoff);
    float qa = bf2f((unsigned short)(q2 & 0xffff));
    float qb = bf2f((unsigned short)(q2 >> 16));
    *(unsigned int*)(QKV + qoff) =
        (unsigned int)f2bf(qa * c - qb * s) |
        ((unsigned int)f2bf(qa * s + qb * c) << 16);
    unsigned int k2 = *(const unsigned int*)(QKV + koff);
    float ka = bf2f((unsigned short)(k2 & 0xffff));
    float kb = bf2f((unsigned short)(k2 >> 16));
    *(unsigned int*)(QKV + koff) =
        (unsigned int)f2bf(ka * c - kb * s) |
        ((unsigned int)f2bf(ka * s + kb * c) << 16);
  } else {
    const unsigned short* Vp = QKV + (size_t)32 * Ntok * 64;
    int b2 = blk - ropeB;
    int h = b2 & 15, t0 = (b2 >> 4) * 64;
    {
      int tok = tid >> 2, dc = (tid & 3) * 16;
      const unsigned short* src = Vp + ((size_t)h * Ntok + t0 + tok) * 64 + dc;
      *(s16x8*)&tile[tok][dc]     = *(const s16x8*)src;
      *(s16x8*)&tile[tok][dc + 8] = *(const s16x8*)(src + 8);
    }
    __syncthreads();
    {
      int d = tid >> 2, tc = (tid & 3) * 16;
      s16x8 o0, o1;
#pragma unroll
      for (int j = 0; j < 8; ++j) {
        o0[j] = (short)tile[tc + j][d];
        o1[j] = (short)tile[tc + 8 + j][d];
      }
      unsigned short* dst = VtG + (size_t)(h * 64 + d) * Ntok + t0 + tc;
      *(s16x8*)dst       = o0;
      *(s16x8*)(dst + 8) = o1;
    }
  }
}

// ---------------------------------------------------------------------------
// Flash attention (R14/R17/R19-verified).  Block = (batch, head, 64 q rows);
// 4 waves x 16 q rows.  Pair-major enumeration (verified optimum).
// S^T = K*Q^T; online softmax (log2, lazy defer-max, row-sums via
// ones-MFMA); K/VtG staged in LDS; raw-barrier pipeline with reg prefetch;
// pair->XCD mapping (balanced + L2-local).  launch_bounds (256,4) verified:
// (256,8) spills (R22), (128,4) spills (R4).
// ---------------------------------------------------------------------------
__global__ __launch_bounds__(256, 4) void attn_kernel(
    const unsigned short* __restrict__ QKV,
    const unsigned short* __restrict__ VtG, const int* __restrict__ boff,
    unsigned short* __restrict__ O, int Ntok) {
  __shared__ unsigned short Klds[64][72];
  __shared__ unsigned short Vt[64][72];   // Vt[d][key]
  const float SCALE_LOG2 = 0.125f * 1.44269504088896340736f;
  const s16x4 ones16 = {(short)0x3F80, (short)0x3F80, (short)0x3F80, (short)0x3F80};

  // pair-major mapping: grid = 2048 = 8 xcd * 16 pairs * 16 qblk
  int bid = blockIdx.x;
  int x = bid & 7, i = bid >> 3;
  int qblk = i & 15;
  int p = x + 8 * (i >> 4);               // (b,h) pair, resident on XCD x
  int h = p & 15, b = p >> 4;
  int off = boff[b], len = boff[b + 1] - off;
  int q0 = qblk * 64;
  if (q0 >= len) return;
  int t = threadIdx.x, lane = t & 63, wave = t >> 6;
  int r = lane & 15, g4 = lane >> 4;
  const unsigned short* Qg = QKV + (size_t)h * Ntok * 64;
  const unsigned short* Kg = QKV + (size_t)(16 + h) * Ntok * 64;
  int qmax = off + len - 1;

  bf16x8 qf[2];
  {
    int qtok = off + q0 + wave * 16 + r;
    if (qtok > qmax) qtok = qmax;
#pragma unroll
    for (int c = 0; c < 2; ++c)
      qf[c] = *(const bf16x8*)(Qg + (size_t)qtok * 64 + c * 32 + g4 * 8);
  }

  float m = -1e30f;
  f32x4 o[4] = {};
  f32x4 o_sum = {};                       // row-sums of P via ones-MFMA

  // staging (256 threads): thread t stages K row t>>2 shorts [(t&3)*16,+16)
  // and Vt row t>>2 keys [(t&3)*16,+16).
  int srow = t >> 2, sseg = t & 3;
  const unsigned short* Vrow = VtG + (size_t)(h * 64 + srow) * Ntok;

  s16x8 kr[2], vr[2];
  {
    int ktok = off + srow; if (ktok > qmax) ktok = qmax;
#pragma unroll
    for (int c = 0; c < 2; ++c)
      kr[c] = *(const s16x8*)(Kg + (size_t)ktok * 64 + sseg * 16 + c * 8);
#pragma unroll
    for (int c = 0; c < 2; ++c) {
      int tc = sseg * 16 + c * 8; if (tc + 8 > len) tc = len - 8;
      vr[c] = *(const s16x8*)(Vrow + off + tc);
    }
  }

  for (int kt = 0; kt < len; kt += 64) {
    // (A) previous tile's LDS reads complete
    asm volatile("s_waitcnt lgkmcnt(0)" ::: "memory");
    __builtin_amdgcn_s_barrier();
    __builtin_amdgcn_sched_barrier(0);
#pragma unroll
    for (int c = 0; c < 2; ++c) {
      *(s16x8*)&Klds[srow][sseg * 16 + c * 8] = kr[c];
      *(s16x8*)&Vt[srow][sseg * 16 + c * 8]   = vr[c];
    }
    int ktn = kt + 64;
    if (ktn < len) {   // issue prefetch; stays in flight through compute
      int ktok = off + ktn + srow; if (ktok > qmax) ktok = qmax;
#pragma unroll
      for (int c = 0; c < 2; ++c)
        kr[c] = *(const s16x8*)(Kg + (size_t)ktok * 64 + sseg * 16 + c * 8);
#pragma unroll
      for (int c = 0; c < 2; ++c) {
        int tc = ktn + sseg * 16 + c * 8; if (tc + 8 > len) tc = len - 8;
        vr[c] = *(const s16x8*)(Vrow + off + tc);
      }
    }
    // (B) own ds_writes visible; do NOT drain vmcnt (prefetch stays async)
    asm volatile("s_waitcnt lgkmcnt(0)" ::: "memory");
    __builtin_amdgcn_s_barrier();
    __builtin_amdgcn_sched_barrier(0);

    // ---- scores: S^T[key][q], 64 keys x 16 q rows -----------------------
    f32x4 s[4];
    __builtin_amdgcn_s_setprio(1);
#pragma unroll
    for (int sub = 0; sub < 4; ++sub) {
      bf16x8 ka0 = *(const bf16x8*)(&Klds[sub * 16 + r][g4 * 8]);
      bf16x8 ka1 = *(const bf16x8*)(&Klds[sub * 16 + r][32 + g4 * 8]);
      f32x4 acc = {};
      acc = mfma32(ka0, qf[0], acc);
      acc = mfma32(ka1, qf[1], acc);
      s[sub] = acc;
    }
    __builtin_amdgcn_s_setprio(0);

    bool tail = (kt + 64 > len);
    s16x4 pf[4];
    {
      float sc[4][4];                      // raw scores (masked)
      float ms[4];
#pragma unroll
      for (int sub = 0; sub < 4; ++sub) {
#pragma unroll
        for (int e = 0; e < 4; ++e) {
          float v = s[sub][e];
          if (tail && (kt + sub * 16 + 4 * g4 + e >= len)) v = -1e30f;
          sc[sub][e] = v;
        }
        ms[sub] = fmaxf(fmaxf(sc[sub][0], sc[sub][1]),
                        fmaxf(sc[sub][2], sc[sub][3]));
      }
      float tmax = fmaxf(fmaxf(ms[0], ms[1]), fmaxf(ms[2], ms[3]));
      // lazy defer-max: per-lane check, no shuffles in the common case
      if (!__all(tmax * SCALE_LOG2 <= m + 8.f)) {
        float tm = tmax * SCALE_LOG2;
        tm = fmaxf(tm, __shfl_xor(tm, 16));
        tm = fmaxf(tm, __shfl_xor(tm, 32));
        float mnew = fmaxf(m, tm);
        float alpha = exp2f(m - mnew);     // wave-uniform
        m = mnew;
#pragma unroll
        for (int e = 0; e < 4; ++e) o_sum[e] *= alpha;
#pragma unroll
        for (int dt = 0; dt < 4; ++dt)
#pragma unroll
          for (int e = 0; e < 4; ++e) o[dt][e] *= alpha;
      }
#pragma unroll
      for (int sub = 0; sub < 4; ++sub) {
        bf16x4 pb;
#pragma unroll
        for (int e = 0; e < 4; ++e)
          pb[e] = (__bf16)exp2f(fmaf(sc[sub][e], SCALE_LOG2, -m));
        pf[sub] = __builtin_bit_cast(s16x4, pb);
      }
    }

    // ---- PV: O += P * V ; row-sums via ones-MFMA ------------------------
    __builtin_amdgcn_s_setprio(1);
#pragma unroll
    for (int sub = 0; sub < 4; ++sub)
      o_sum = mfma16(pf[sub], ones16, o_sum);
#pragma unroll
    for (int dt = 0; dt < 4; ++dt)
#pragma unroll
      for (int sub = 0; sub < 4; ++sub) {
        s16x4 vf = *(const s16x4*)(&Vt[dt * 16 + r][sub * 16 + 4 * g4]);
        o[dt] = mfma16(pf[sub], vf, o[dt]);
      }
    __builtin_amdgcn_s_setprio(0);
  }

  {
    float il[4];
#pragma unroll
    for (int e = 0; e < 4; ++e) il[e] = 1.0f / o_sum[e];
#pragma unroll
    for (int dt = 0; dt < 4; ++dt)
#pragma unroll
      for (int e = 0; e < 4; ++e) {
        int tl = q0 + wave * 16 + 4 * g4 + e;
        if (tl < len)
          O[(size_t)(off + tl) * 1024 + h * 64 + dt * 16 + r] =
              f2bf(o[dt][e] * il[e]);
      }
  }
}

// ---------------------------------------------------------------------------
extern "C" void kernel_launch(void* const* d_in, const int* in_sizes, int n_in,
                              void* d_out, int out_size, void* d_ws, size_t ws_size,
                              hipStream_t stream) {
  const float* x     = (const float*)d_in[0];
  const float* pos   = (const float*)d_in[1];
  const int*   boff  = (const int*)d_in[2];
  const float* gamma = (const float*)d_in[3];
  const float* beta  = (const float*)d_in[4];
  const float* wqkv  = (const float*)d_in[5];
  const float* wout  = (const float*)d_in[6];
  const float* freqs = (const float*)d_in[7];
  float* out = (float*)d_out;
  int N  = in_sizes[0] / 1024;   // 6144
  int Bn = in_sizes[2] - 1;      // 8

  char* ws = (char*)d_ws;
  unsigned short* wqkvT = (unsigned short*)ws;                          // 6 MiB
  unsigned short* woutT = (unsigned short*)(ws + (size_t)3072 * 1024 * 2);
  unsigned short* QKV   = (unsigned short*)(ws + (size_t)3072 * 1024 * 2 +
                                            (size_t)1024 * 1024 * 2);
  size_t qkvBytes = (size_t)48 * N * 64 * 2;                            // 36 MiB
  unsigned short* hbuf = (unsigned short*)((char*)QKV + qkvBytes);      // 12 MiB
  unsigned short* VtG  = hbuf;                       // hbuf dead after gemm_qkv
  unsigned short* Vp   = QKV + (size_t)32 * N * 64;  // V plane (row-major)
  unsigned short* Obuf = Vp;                         // V plane dead after vtrans

  fused_pre<<<N / 4 + 768 + 256, 256, 0, stream>>>(
      x, gamma, beta, hbuf, wqkv, wqkvT, wout, woutT, N);
  gemm_qkv<<<dim3(3072 / 128, N / 128), 256, 0, stream>>>(
      hbuf, wqkvT, QKV, N, 1024);
  rope_vtrans<<<N * 2 + 16 * (N / 64), 256, 0, stream>>>(
      QKV, VtG, pos, freqs, N);
  attn_kernel<<<8 * 16 * 16, 256, 0, stream>>>(QKV, VtG, boff, Obuf, N);
  gemm_out64<<<dim3(1024 / 128, N / 64), 256, 0, stream>>>(
      Obuf, woutT, x, out, N, 1024, 1024);
}

// Round 24
// 168.276 us; speedup vs baseline: 1.4085x; 1.0082x over previous
//
#include <hip/hip_runtime.h>

// ---------------------------------------------------------------------------
// MultilevelSelfAttentionBlockWithRoPE on MI355X (gfx950)
// fused_pre(LN + W transposes) -> QKV GEMM (BK=64, XCD-swizzled) -> fused
// rope+vtrans -> flash attn (64-key tiles, 4 waves x 16 q, pair-major) ->
// out GEMM (64x128, BK=64, XCD-swizzled) + residual.
// R24 = R19/R21/R23 (verified best 169.7, 4x) + T1 XCD swizzle on both
// GEMMs (bijective remaps: 1152%8==0, 768%8==0).
// Rationale: gemm_qkv FETCH 55.7MB vs 19MB unique inputs; R9 exonerated
// stores -> excess is cross-XCD A-panel re-fetch (default round-robin puts
// the 8 same-m blocks on 8 L2s).  Contiguous-chunk-per-XCD makes A-panels
// XCD-private -> fewer L2 misses -> shorter vmcnt drains at barriers.
// ---------------------------------------------------------------------------

typedef float  f32x4  __attribute__((ext_vector_type(4)));
typedef __bf16 bf16x8 __attribute__((ext_vector_type(8)));
typedef __bf16 bf16x4 __attribute__((ext_vector_type(4)));
typedef short  s16x4  __attribute__((ext_vector_type(4)));
typedef short  s16x8  __attribute__((ext_vector_type(8)));
typedef unsigned short u16x4 __attribute__((ext_vector_type(4)));

typedef __attribute__((address_space(1))) void as1_void_t;
typedef __attribute__((address_space(3))) void as3_void_t;

static __device__ __forceinline__ unsigned short f2bf(float f) {
  unsigned int u = __float_as_uint(f);
  u += 0x7fffu + ((u >> 16) & 1u);          // round-to-nearest-even
  return (unsigned short)(u >> 16);
}
static __device__ __forceinline__ float bf2f(unsigned short s) {
  return __uint_as_float(((unsigned int)s) << 16);
}

static __device__ __forceinline__ void gload_lds16(const void* g, void* l) {
  __builtin_amdgcn_global_load_lds((as1_void_t*)g, (as3_void_t*)l, 16, 0, 0);
}

static __device__ __forceinline__ f32x4 mfma32(bf16x8 a, bf16x8 b, f32x4 c) {
  return __builtin_amdgcn_mfma_f32_16x16x32_bf16(a, b, c, 0, 0, 0);
}
static __device__ __forceinline__ f32x4 mfma16(s16x4 a, s16x4 b, f32x4 c) {
  return __builtin_amdgcn_mfma_f32_16x16x16bf16_1k(a, b, c, 0, 0, 0);
}

// ---------------------------------------------------------------------------
// fused_pre: LN (blocks [0, N/4)) + wqkv transpose (next 768) + wout
// transpose (next 256).  Block-uniform dispatch; all paths 256 threads.
// ---------------------------------------------------------------------------
__global__ __launch_bounds__(256) void fused_pre(
    const float* __restrict__ x, const float* __restrict__ gamma,
    const float* __restrict__ beta, unsigned short* __restrict__ h,
    const float* __restrict__ wqkv, unsigned short* __restrict__ wqkvT,
    const float* __restrict__ wout, unsigned short* __restrict__ woutT,
    int Ntok) {
  __shared__ unsigned short tile[64][65];
  int blk = blockIdx.x, t = threadIdx.x;
  int lnB = Ntok >> 2;
  if (blk < lnB) {
    // ---- LayerNorm: one wave per row ----
    int row  = blk * 4 + (t >> 6);
    int lane = t & 63;
    const float* xr = x + (size_t)row * 1024;
    f32x4 v[4];
    float s = 0.f, ss = 0.f;
#pragma unroll
    for (int c = 0; c < 4; ++c) {
      v[c] = *(const f32x4*)(xr + c * 256 + lane * 4);
#pragma unroll
      for (int j = 0; j < 4; ++j) { s += v[c][j]; ss += v[c][j] * v[c][j]; }
    }
#pragma unroll
    for (int d = 1; d < 64; d <<= 1) {
      s  += __shfl_xor(s, d);
      ss += __shfl_xor(ss, d);
    }
    float mu  = s * (1.f / 1024.f);
    float var = ss * (1.f / 1024.f) - mu * mu;
    float inv = rsqrtf(var + 1e-5f);
#pragma unroll
    for (int c = 0; c < 4; ++c) {
      f32x4 gv = *(const f32x4*)(gamma + c * 256 + lane * 4);
      f32x4 bv = *(const f32x4*)(beta  + c * 256 + lane * 4);
      u16x4 hv;
#pragma unroll
      for (int j = 0; j < 4; ++j)
        hv[j] = f2bf((v[c][j] - mu) * inv * gv[j] + bv[j]);
      *(u16x4*)(h + (size_t)row * 1024 + c * 256 + lane * 4) = hv;
    }
  } else {
    // ---- transpose+convert f32 [R][C] -> bf16 [C][R] ----
    const float* in;
    unsigned short* out;
    int R = 1024, C, c0, r0;
    if (blk < lnB + 768) {
      int idx = blk - lnB;
      in = wqkv; out = wqkvT; C = 3072;
      c0 = (idx % 48) * 64; r0 = (idx / 48) * 64;
    } else {
      int idx = blk - lnB - 768;
      in = wout; out = woutT; C = 1024;
      c0 = (idx & 15) * 64; r0 = (idx >> 4) * 64;
    }
    int tr = t >> 6, tc = t & 63;
#pragma unroll
    for (int i = 0; i < 16; ++i) {
      int rr = i * 4 + tr;
      tile[tc][rr] = f2bf(in[(size_t)(r0 + rr) * C + c0 + tc]);
    }
    __syncthreads();
#pragma unroll
    for (int i = 0; i < 16; ++i) {
      int cc = i * 4 + tr;
      out[(size_t)(c0 + cc) * R + r0 + tc] = tile[cc][tc];
    }
  }
}

// ---------------------------------------------------------------------------
// GEMM (QKV): C = A * Bt^T, scatter bf16 into QKV planes [3][16][M][64].
// BK=64 as two BK-32 subtiles (R16-verified).  R24: T1 XCD swizzle —
// each XCD gets a contiguous chunk of the linearized grid (A-panels
// XCD-private).  Bijective: 1152 % 8 == 0.
// ---------------------------------------------------------------------------
__global__ __launch_bounds__(256) void gemm_qkv(
    const unsigned short* __restrict__ A, const unsigned short* __restrict__ Bt,
    unsigned short* __restrict__ Cqkv, int M, int K) {
  __shared__ unsigned short Alds[2][128 * 32];
  __shared__ unsigned short Blds[2][128 * 32];
  int nb  = gridDim.x * gridDim.y;
  int cpx = nb >> 3;
  int bidl = blockIdx.x + blockIdx.y * gridDim.x;
  int sw = (bidl & 7) * cpx + (bidl >> 3);
  int n0 = (sw % gridDim.x) * 128, m0 = (sw / gridDim.x) * 128;
  int t = threadIdx.x, lane = t & 63, wave = t >> 6;
  int wr = wave >> 1, wc = wave & 1;
  int r = lane & 15, g = lane >> 4;
  f32x4 acc[4][4] = {};

  int srow = lane >> 2;
  int scol = (lane & 3) * 8;

  for (int k0 = 0; k0 < K; k0 += 64) {
    __syncthreads();
#pragma unroll
    for (int half = 0; half < 2; ++half)
#pragma unroll
      for (int c = 0; c < 2; ++c) {
        int seg = wave * 2 + c;
        gload_lds16(A  + (size_t)(m0 + seg * 16 + srow) * K + k0 + half * 32 + scol,
                    Alds[half] + seg * 16 * 32);
        gload_lds16(Bt + (size_t)(n0 + seg * 16 + srow) * K + k0 + half * 32 + scol,
                    Blds[half] + seg * 16 * 32);
      }
    __syncthreads();
#pragma unroll
    for (int half = 0; half < 2; ++half) {
      bf16x8 a[4], b[4];
#pragma unroll
      for (int m = 0; m < 4; ++m)
        a[m] = *(const bf16x8*)(Alds[half] + (wr * 64 + m * 16 + r) * 32 + g * 8);
#pragma unroll
      for (int n = 0; n < 4; ++n)
        b[n] = *(const bf16x8*)(Blds[half] + (wc * 64 + n * 16 + r) * 32 + g * 8);
#pragma unroll
      for (int m = 0; m < 4; ++m)
#pragma unroll
        for (int n = 0; n < 4; ++n)
          acc[m][n] = mfma32(a[m], b[n], acc[m][n]);
    }
  }

#pragma unroll
  for (int mi = 0; mi < 4; ++mi) {
    int grow0 = m0 + wr * 64 + mi * 16 + g * 4;
#pragma unroll
    for (int ni = 0; ni < 4; ++ni) {
      int gcol = n0 + wc * 64 + ni * 16 + r;
      f32x4 v = acc[mi][ni];
#pragma unroll
      for (int e = 0; e < 4; ++e) {
        int which = gcol >> 10, rem = gcol & 1023, hh = rem >> 6, d = rem & 63;
        Cqkv[((size_t)(which * 16 + hh) * M + grow0 + e) * 64 + d] = f2bf(v[e]);
      }
    }
  }
}

// ---------------------------------------------------------------------------
// out-GEMM: Cf = A * Bt^T + residual.  64x128 tile, BK=64 (two subtiles),
// 768 blocks = 3/CU.  R24: T1 XCD swizzle (bijective: 768 % 8 == 0).
// ---------------------------------------------------------------------------
__global__ __launch_bounds__(256) void gemm_out64(
    const unsigned short* __restrict__ A, const unsigned short* __restrict__ Bt,
    const float* __restrict__ residual, float* __restrict__ Cf,
    int M, int Ncols, int K) {
  __shared__ unsigned short Alds[2][64 * 32];
  __shared__ unsigned short Blds[2][128 * 32];
  int nb  = gridDim.x * gridDim.y;
  int cpx = nb >> 3;
  int bidl = blockIdx.x + blockIdx.y * gridDim.x;
  int sw = (bidl & 7) * cpx + (bidl >> 3);
  int n0 = (sw % gridDim.x) * 128, m0 = (sw / gridDim.x) * 64;
  int t = threadIdx.x, lane = t & 63, wave = t >> 6;
  int wr = wave >> 1, wc = wave & 1;
  int r = lane & 15, g = lane >> 4;
  f32x4 acc[2][4] = {};

  int srow = lane >> 2;
  int scol = (lane & 3) * 8;

  for (int k0 = 0; k0 < K; k0 += 64) {
    __syncthreads();
#pragma unroll
    for (int half = 0; half < 2; ++half) {
      gload_lds16(A + (size_t)(m0 + wave * 16 + srow) * K + k0 + half * 32 + scol,
                  Alds[half] + wave * 16 * 32);
#pragma unroll
      for (int c = 0; c < 2; ++c) {
        int seg = wave * 2 + c;
        gload_lds16(Bt + (size_t)(n0 + seg * 16 + srow) * K + k0 + half * 32 + scol,
                    Blds[half] + seg * 16 * 32);
      }
    }
    __syncthreads();
#pragma unroll
    for (int half = 0; half < 2; ++half) {
      bf16x8 a[2], b[4];
#pragma unroll
      for (int m = 0; m < 2; ++m)
        a[m] = *(const bf16x8*)(Alds[half] + (wr * 32 + m * 16 + r) * 32 + g * 8);
#pragma unroll
      for (int n = 0; n < 4; ++n)
        b[n] = *(const bf16x8*)(Blds[half] + (wc * 64 + n * 16 + r) * 32 + g * 8);
#pragma unroll
      for (int m = 0; m < 2; ++m)
#pragma unroll
        for (int n = 0; n < 4; ++n)
          acc[m][n] = mfma32(a[m], b[n], acc[m][n]);
    }
  }

#pragma unroll
  for (int mi = 0; mi < 2; ++mi) {
    int grow0 = m0 + wr * 32 + mi * 16 + g * 4;
#pragma unroll
    for (int ni = 0; ni < 4; ++ni) {
      int gcol = n0 + wc * 64 + ni * 16 + r;
      f32x4 v = acc[mi][ni];
#pragma unroll
      for (int e = 0; e < 4; ++e)
        Cf[(size_t)(grow0 + e) * Ncols + gcol] =
            v[e] + residual[(size_t)(grow0 + e) * Ncols + gcol];
    }
  }
}

// ---------------------------------------------------------------------------
// rope_vtrans: RoPE on Q,K planes (blocks [0, N*2)) + V transpose into VtG
// (blocks [N*2, N*2 + 16*N/64)).  Block-uniform dispatch, 256 threads.
// ---------------------------------------------------------------------------
__global__ __launch_bounds__(256) void rope_vtrans(
    unsigned short* __restrict__ QKV, unsigned short* __restrict__ VtG,
    const float* __restrict__ pos, const float* __restrict__ freqs, int Ntok) {
  __shared__ unsigned short tile[64][72];
  int blk = blockIdx.x, tid = threadIdx.x;
  int ropeB = Ntok * 2;                   // (Ntok*512)/256
  if (blk < ropeB) {
    int t = blk * 256 + tid;
    int kk = t & 31, h = (t >> 5) & 15, i = t >> 9;
    float lvlf = pos[i * 3 + 0];
    float py   = pos[i * 3 + 1];
    float px   = pos[i * 3 + 2];
    int lvl = (int)lvlf;
    lvl = lvl < 0 ? 0 : (lvl > 3 ? 3 : lvl);
    const float* fp = freqs + (((lvl * 16 + h) * 32 + kk) << 1);
    float ang = fp[0] * py + fp[1] * px;
    float s, c;
    __sincosf(ang, &s, &c);
    size_t qoff = ((size_t)h * Ntok + i) * 64 + 2 * kk;
    size_t koff = qoff + (size_t)16 * Ntok * 64;
    unsigned int q2 = *(const unsigned int*)(QKV + qoff);
    float qa = bf2f((unsigned short)(q2 & 0xffff));
    float qb = bf2f((unsigned short)(q2 >> 16));
    *(unsigned int*)(QKV + qoff) =
        (unsigned int)f2bf(qa * c - qb * s) |
        ((unsigned int)f2bf(qa * s + qb * c) << 16);
    unsigned int k2 = *(const unsigned int*)(QKV + koff);
    float ka = bf2f((unsigned short)(k2 & 0xffff));
    float kb = bf2f((unsigned short)(k2 >> 16));
    *(unsigned int*)(QKV + koff) =
        (unsigned int)f2bf(ka * c - kb * s) |
        ((unsigned int)f2bf(ka * s + kb * c) << 16);
  } else {
    const unsigned short* Vp = QKV + (size_t)32 * Ntok * 64;
    int b2 = blk - ropeB;
    int h = b2 & 15, t0 = (b2 >> 4) * 64;
    {
      int tok = tid >> 2, dc = (tid & 3) * 16;
      const unsigned short* src = Vp + ((size_t)h * Ntok + t0 + tok) * 64 + dc;
      *(s16x8*)&tile[tok][dc]     = *(const s16x8*)src;
      *(s16x8*)&tile[tok][dc + 8] = *(const s16x8*)(src + 8);
    }
    __syncthreads();
    {
      int d = tid >> 2, tc = (tid & 3) * 16;
      s16x8 o0, o1;
#pragma unroll
      for (int j = 0; j < 8; ++j) {
        o0[j] = (short)tile[tc + j][d];
        o1[j] = (short)tile[tc + 8 + j][d];
      }
      unsigned short* dst = VtG + (size_t)(h * 64 + d) * Ntok + t0 + tc;
      *(s16x8*)dst       = o0;
      *(s16x8*)(dst + 8) = o1;
    }
  }
}

// ---------------------------------------------------------------------------
// Flash attention (R14/R17/R19-verified).  Block = (batch, head, 64 q rows);
// 4 waves x 16 q rows.  Pair-major enumeration (verified optimum).
// S^T = K*Q^T; online softmax (log2, lazy defer-max, row-sums via
// ones-MFMA); K/VtG staged in LDS; raw-barrier pipeline with reg prefetch;
// pair->XCD mapping (balanced + L2-local).  launch_bounds (256,4) verified.
// ---------------------------------------------------------------------------
__global__ __launch_bounds__(256, 4) void attn_kernel(
    const unsigned short* __restrict__ QKV,
    const unsigned short* __restrict__ VtG, const int* __restrict__ boff,
    unsigned short* __restrict__ O, int Ntok) {
  __shared__ unsigned short Klds[64][72];
  __shared__ unsigned short Vt[64][72];   // Vt[d][key]
  const float SCALE_LOG2 = 0.125f * 1.44269504088896340736f;
  const s16x4 ones16 = {(short)0x3F80, (short)0x3F80, (short)0x3F80, (short)0x3F80};

  // pair-major mapping: grid = 2048 = 8 xcd * 16 pairs * 16 qblk
  int bid = blockIdx.x;
  int x = bid & 7, i = bid >> 3;
  int qblk = i & 15;
  int p = x + 8 * (i >> 4);               // (b,h) pair, resident on XCD x
  int h = p & 15, b = p >> 4;
  int off = boff[b], len = boff[b + 1] - off;
  int q0 = qblk * 64;
  if (q0 >= len) return;
  int t = threadIdx.x, lane = t & 63, wave = t >> 6;
  int r = lane & 15, g4 = lane >> 4;
  const unsigned short* Qg = QKV + (size_t)h * Ntok * 64;
  const unsigned short* Kg = QKV + (size_t)(16 + h) * Ntok * 64;
  int qmax = off + len - 1;

  bf16x8 qf[2];
  {
    int qtok = off + q0 + wave * 16 + r;
    if (qtok > qmax) qtok = qmax;
#pragma unroll
    for (int c = 0; c < 2; ++c)
      qf[c] = *(const bf16x8*)(Qg + (size_t)qtok * 64 + c * 32 + g4 * 8);
  }

  float m = -1e30f;
  f32x4 o[4] = {};
  f32x4 o_sum = {};                       // row-sums of P via ones-MFMA

  // staging (256 threads): thread t stages K row t>>2 shorts [(t&3)*16,+16)
  // and Vt row t>>2 keys [(t&3)*16,+16).
  int srow = t >> 2, sseg = t & 3;
  const unsigned short* Vrow = VtG + (size_t)(h * 64 + srow) * Ntok;

  s16x8 kr[2], vr[2];
  {
    int ktok = off + srow; if (ktok > qmax) ktok = qmax;
#pragma unroll
    for (int c = 0; c < 2; ++c)
      kr[c] = *(const s16x8*)(Kg + (size_t)ktok * 64 + sseg * 16 + c * 8);
#pragma unroll
    for (int c = 0; c < 2; ++c) {
      int tc = sseg * 16 + c * 8; if (tc + 8 > len) tc = len - 8;
      vr[c] = *(const s16x8*)(Vrow + off + tc);
    }
  }

  for (int kt = 0; kt < len; kt += 64) {
    // (A) previous tile's LDS reads complete
    asm volatile("s_waitcnt lgkmcnt(0)" ::: "memory");
    __builtin_amdgcn_s_barrier();
    __builtin_amdgcn_sched_barrier(0);
#pragma unroll
    for (int c = 0; c < 2; ++c) {
      *(s16x8*)&Klds[srow][sseg * 16 + c * 8] = kr[c];
      *(s16x8*)&Vt[srow][sseg * 16 + c * 8]   = vr[c];
    }
    int ktn = kt + 64;
    if (ktn < len) {   // issue prefetch; stays in flight through compute
      int ktok = off + ktn + srow; if (ktok > qmax) ktok = qmax;
#pragma unroll
      for (int c = 0; c < 2; ++c)
        kr[c] = *(const s16x8*)(Kg + (size_t)ktok * 64 + sseg * 16 + c * 8);
#pragma unroll
      for (int c = 0; c < 2; ++c) {
        int tc = ktn + sseg * 16 + c * 8; if (tc + 8 > len) tc = len - 8;
        vr[c] = *(const s16x8*)(Vrow + off + tc);
      }
    }
    // (B) own ds_writes visible; do NOT drain vmcnt (prefetch stays async)
    asm volatile("s_waitcnt lgkmcnt(0)" ::: "memory");
    __builtin_amdgcn_s_barrier();
    __builtin_amdgcn_sched_barrier(0);

    // ---- scores: S^T[key][q], 64 keys x 16 q rows -----------------------
    f32x4 s[4];
    __builtin_amdgcn_s_setprio(1);
#pragma unroll
    for (int sub = 0; sub < 4; ++sub) {
      bf16x8 ka0 = *(const bf16x8*)(&Klds[sub * 16 + r][g4 * 8]);
      bf16x8 ka1 = *(const bf16x8*)(&Klds[sub * 16 + r][32 + g4 * 8]);
      f32x4 acc = {};
      acc = mfma32(ka0, qf[0], acc);
      acc = mfma32(ka1, qf[1], acc);
      s[sub] = acc;
    }
    __builtin_amdgcn_s_setprio(0);

    bool tail = (kt + 64 > len);
    s16x4 pf[4];
    {
      float sc[4][4];                      // raw scores (masked)
      float ms[4];
#pragma unroll
      for (int sub = 0; sub < 4; ++sub) {
#pragma unroll
        for (int e = 0; e < 4; ++e) {
          float v = s[sub][e];
          if (tail && (kt + sub * 16 + 4 * g4 + e >= len)) v = -1e30f;
          sc[sub][e] = v;
        }
        ms[sub] = fmaxf(fmaxf(sc[sub][0], sc[sub][1]),
                        fmaxf(sc[sub][2], sc[sub][3]));
      }
      float tmax = fmaxf(fmaxf(ms[0], ms[1]), fmaxf(ms[2], ms[3]));
      // lazy defer-max: per-lane check, no shuffles in the common case
      if (!__all(tmax * SCALE_LOG2 <= m + 8.f)) {
        float tm = tmax * SCALE_LOG2;
        tm = fmaxf(tm, __shfl_xor(tm, 16));
        tm = fmaxf(tm, __shfl_xor(tm, 32));
        float mnew = fmaxf(m, tm);
        float alpha = exp2f(m - mnew);     // wave-uniform
        m = mnew;
#pragma unroll
        for (int e = 0; e < 4; ++e) o_sum[e] *= alpha;
#pragma unroll
        for (int dt = 0; dt < 4; ++dt)
#pragma unroll
          for (int e = 0; e < 4; ++e) o[dt][e] *= alpha;
      }
#pragma unroll
      for (int sub = 0; sub < 4; ++sub) {
        bf16x4 pb;
#pragma unroll
        for (int e = 0; e < 4; ++e)
          pb[e] = (__bf16)exp2f(fmaf(sc[sub][e], SCALE_LOG2, -m));
        pf[sub] = __builtin_bit_cast(s16x4, pb);
      }
    }

    // ---- PV: O += P * V ; row-sums via ones-MFMA ------------------------
    __builtin_amdgcn_s_setprio(1);
#pragma unroll
    for (int sub = 0; sub < 4; ++sub)
      o_sum = mfma16(pf[sub], ones16, o_sum);
#pragma unroll
    for (int dt = 0; dt < 4; ++dt)
#pragma unroll
      for (int sub = 0; sub < 4; ++sub) {
        s16x4 vf = *(const s16x4*)(&Vt[dt * 16 + r][sub * 16 + 4 * g4]);
        o[dt] = mfma16(pf[sub], vf, o[dt]);
      }
    __builtin_amdgcn_s_setprio(0);
  }

  {
    float il[4];
#pragma unroll
    for (int e = 0; e < 4; ++e) il[e] = 1.0f / o_sum[e];
#pragma unroll
    for (int dt = 0; dt < 4; ++dt)
#pragma unroll
      for (int e = 0; e < 4; ++e) {
        int tl = q0 + wave * 16 + 4 * g4 + e;
        if (tl < len)
          O[(size_t)(off + tl) * 1024 + h * 64 + dt * 16 + r] =
              f2bf(o[dt][e] * il[e]);
      }
  }
}

// ---------------------------------------------------------------------------
extern "C" void kernel_launch(void* const* d_in, const int* in_sizes, int n_in,
                              void* d_out, int out_size, void* d_ws, size_t ws_size,
                              hipStream_t stream) {
  const float* x     = (const float*)d_in[0];
  const float* pos   = (const float*)d_in[1];
  const int*   boff  = (const int*)d_in[2];
  const float* gamma = (const float*)d_in[3];
  const float* beta  = (const float*)d_in[4];
  const float* wqkv  = (const float*)d_in[5];
  const float* wout  = (const float*)d_in[6];
  const float* freqs = (const float*)d_in[7];
  float* out = (float*)d_out;
  int N  = in_sizes[0] / 1024;   // 6144
  int Bn = in_sizes[2] - 1;      // 8

  char* ws = (char*)d_ws;
  unsigned short* wqkvT = (unsigned short*)ws;                          // 6 MiB
  unsigned short* woutT = (unsigned short*)(ws + (size_t)3072 * 1024 * 2);
  unsigned short* QKV   = (unsigned short*)(ws + (size_t)3072 * 1024 * 2 +
                                            (size_t)1024 * 1024 * 2);
  size_t qkvBytes = (size_t)48 * N * 64 * 2;                            // 36 MiB
  unsigned short* hbuf = (unsigned short*)((char*)QKV + qkvBytes);      // 12 MiB
  unsigned short* VtG  = hbuf;                       // hbuf dead after gemm_qkv
  unsigned short* Vp   = QKV + (size_t)32 * N * 64;  // V plane (row-major)
  unsigned short* Obuf = Vp;                         // V plane dead after vtrans

  fused_pre<<<N / 4 + 768 + 256, 256, 0, stream>>>(
      x, gamma, beta, hbuf, wqkv, wqkvT, wout, woutT, N);
  gemm_qkv<<<dim3(3072 / 128, N / 128), 256, 0, stream>>>(
      hbuf, wqkvT, QKV, N, 1024);
  rope_vtrans<<<N * 2 + 16 * (N / 64), 256, 0, stream>>>(
      QKV, VtG, pos, freqs, N);
  attn_kernel<<<8 * 16 * 16, 256, 0, stream>>>(QKV, VtG, boff, Obuf, N);
  gemm_out64<<<dim3(1024 / 128, N / 64), 256, 0, stream>>>(
      Obuf, woutT, x, out, N, 1024, 1024);
}